// Round 7
// baseline (11182.072 us; speedup 1.0000x reference)
//
#include <hip/hip_runtime.h>
#include <cmath>

#define BATCH 4
#define TSEQ  128
#define HH    100
#define WW    464
#define CC    128
#define EMBD  300
#define HIDD  600
#define GATE4 2400
#define NPIX  (HH*WW)                 // 46400
#define IMG   ((size_t)BATCH*NPIX*CC) // 23,756,800 floats

// ---- workspace layout (in floats) ----
#define OFF_A  ((size_t)0)
#define OFF_B  (IMG)
#define OFF_C  (2*IMG)                // WhT (11.5MB) overlaid here until chanmul
#define OFF_XG (3*IMG)
#define SZ_XG  ((size_t)2*BATCH*TSEQ*GATE4)   // 2,457,600
#define OFF_H  (OFF_XG + SZ_XG)
#define SZ_H   ((size_t)2*2*BATCH*HIDD)        // 9600 (parity,dir,b,u)
#define OFF_CS (OFF_H + SZ_H)                  // barrier ints live here (zeroed)
#define SZ_CS  ((size_t)2*BATCH*HIDD)
#define OFF_TS (OFF_CS + SZ_CS)
#define SZ_TS  ((size_t)2*BATCH*HIDD)          // 4800
#define OFF_K  (OFF_TS + SZ_TS)
#define SZ_K   ((size_t)2*BATCH*CC*CC)         // 131072
#define OFF_W  (OFF_TS + SZ_TS + SZ_K)
#define WSLOT  (25*CC*CC)                      // 409,600 halfs per slot
#define WELEMS (5*WSLOT)                       // 2,048,000 halfs per plane
#define OFF_WH (OFF_W + WELEMS)                // head weights: 65536 halfs (32768 floats)
#define OFF_KF (OFF_WH + 32768)                // chanmul kern frags: 262144 halfs (131072 floats)

typedef _Float16 f16x8 __attribute__((ext_vector_type(8)));
typedef _Float16 f16x4 __attribute__((ext_vector_type(4)));
typedef float    f32x4 __attribute__((ext_vector_type(4)));

__global__ void zero_f(float* p, int n) {
    int i = blockIdx.x*blockDim.x + threadIdx.x;
    if (i < n) p[i] = 0.f;
}

__device__ __forceinline__ void cvt8(float4 v0, float4 v1, f16x8& h, f16x8& l) {
    _Float16 h0=(_Float16)v0.x, h1=(_Float16)v0.y, h2=(_Float16)v0.z, h3=(_Float16)v0.w;
    _Float16 h4=(_Float16)v1.x, h5=(_Float16)v1.y, h6=(_Float16)v1.z, h7=(_Float16)v1.w;
    h = (f16x8){h0,h1,h2,h3,h4,h5,h6,h7};
    l = (f16x8){(_Float16)(v0.x-(float)h0), (_Float16)(v0.y-(float)h1),
                (_Float16)(v0.z-(float)h2), (_Float16)(v0.w-(float)h3),
                (_Float16)(v1.x-(float)h4), (_Float16)(v1.y-(float)h5),
                (_Float16)(v1.z-(float)h6), (_Float16)(v1.w-(float)h7)};
}

// ---- conv weights: fp32 (tap,ic,oc) -> f16 hi/lo FRAGMENT-ORDER planes ----
__global__ void wcvt(const float* __restrict__ c1, const float* __restrict__ c2,
                     const float* __restrict__ dc2, const float* __restrict__ dc1,
                     _Float16* __restrict__ whi, _Float16* __restrict__ wlo)
{
    int e0 = blockIdx.x*256 + threadIdx.x;      // < WELEMS
    int slot = e0 / WSLOT;
    int r = e0 % WSLOT;
    int tap = r >> 14;
    int idx = r & 16383;
    int e    = idx & 7;
    int lane = (idx >> 3) & 63;
    int ni   = (idx >> 9) & 3;
    int kt   = (idx >> 11) & 3;
    int wn   = (idx >> 13) & 1;
    int l15 = lane & 15, kg = lane >> 4;
    int oc = wn*64 + ni*16 + l15;
    int ic = kt*32 + kg*8 + e;
    const float* s; size_t si;
    if      (slot == 0) { s = c1;  si = ((size_t)tap*128 + ic)*128 + oc; }
    else if (slot == 1) { s = c2;  si = ((size_t)tap*128 + ic)*128 + oc; }
    else if (slot == 2) { s = dc2; si = ((size_t)tap*128 + ic)*128 + oc; }
    else if (slot == 3) { s = dc1; si = ((size_t)tap*256 + ic)*128 + oc; }
    else                { s = dc1; si = ((size_t)tap*256 + 128 + ic)*128 + oc; }
    float v = s[si];
    _Float16 h  = (_Float16)v;
    _Float16 lo = (_Float16)(v - (float)h);
    whi[e0] = h; wlo[e0] = lo;
}

// ---- head weights: frag order [which][hi/lo][kt][ni(8)][lane][8]
__global__ void wcvt_head(const float* __restrict__ d1W, const float* __restrict__ d2W,
                          _Float16* __restrict__ whd)
{
    int e0 = blockIdx.x*256 + threadIdx.x;      // < 32768
    int which = e0 >> 14;
    int idx = e0 & 16383;
    int e    = idx & 7;
    int lane = (idx >> 3) & 63;
    int ni   = (idx >> 9) & 7;
    int kt   = (idx >> 12) & 3;
    int l15 = lane & 15, kg = lane >> 4;
    int oc = ni*16 + l15;
    int k  = kt*32 + kg*8 + e;
    const float* W = which ? d2W : d1W;
    float v = W[(size_t)k*CC + oc];
    _Float16 h  = (_Float16)v;
    _Float16 lo = (_Float16)(v - (float)h);
    whd[(size_t)which*32768 + idx]         = h;
    whd[(size_t)which*32768 + 16384 + idx] = lo;
}

// ---- chanmul kernels (runtime): frag order [wb(8)][hi/lo][kt][ni(8)][lane][8]
__global__ void kcvt(const float* __restrict__ kern, _Float16* __restrict__ kf)
{
    int e0 = blockIdx.x*256 + threadIdx.x;      // < 131072
    int wb  = e0 >> 14;                          // which*4 + b
    int idx = e0 & 16383;
    int e = idx & 7, lane = (idx >> 3) & 63, ni = (idx >> 9) & 7, kt = (idx >> 12) & 3;
    int l15 = lane & 15, kg = lane >> 4;
    int oc = ni*16 + l15;
    int k  = kt*32 + kg*8 + e;
    float v = kern[(size_t)wb*16384 + (size_t)k*CC + oc];
    _Float16 h = (_Float16)v;
    kf[(size_t)wb*32768 + idx]         = h;
    kf[(size_t)wb*32768 + 16384 + idx] = (_Float16)(v - (float)h);
}

// ---- Wh transpose: whT[dir][j(2400)][k(600)] = Wh_dir[k][j]
__global__ void wh_t(const float* __restrict__ fWh, const float* __restrict__ bWh,
                     float* __restrict__ whT)
{
    int j = blockIdx.x*256 + threadIdx.x;
    int dir = blockIdx.y;
    if (j >= GATE4) return;
    const float* W = dir ? bWh : fWh;
    float* o = whT + ((size_t)dir*GATE4 + j)*HIDD;
    for (int k = 0; k < HIDD; k += 4) {
        float4 v;
        v.x = W[(size_t)k*GATE4 + j];
        v.y = W[(size_t)(k+1)*GATE4 + j];
        v.z = W[(size_t)(k+2)*GATE4 + j];
        v.w = W[(size_t)(k+3)*GATE4 + j];
        *reinterpret_cast<float4*>(o + k) = v;
    }
}

// text = embed[instr]; xg[dir] = (dir? rev(text):text) @ Wx + b
__global__ void embed_xg(const int* __restrict__ instr, const int* __restrict__ lens,
                         const float* __restrict__ etab,
                         const float* __restrict__ fWx, const float* __restrict__ fb,
                         const float* __restrict__ bWx, const float* __restrict__ bb,
                         float* __restrict__ xg)
{
    int gy  = blockIdx.y;
    int dir = gy >> 5;
    int b   = (gy >> 3) & 3;
    int tt  = gy & 7;
    int t0  = tt*16;
    int j   = blockIdx.x*256 + threadIdx.x;
    __shared__ int tok[16];
    __shared__ __attribute__((aligned(16))) float rows_t[EMBD][16];  // 19.2 KB
    int L = lens[b];
    if (threadIdx.x < 16) {
        int t = t0 + threadIdx.x;
        int tsel = (dir == 1 && t < L) ? (L - 1 - t) : t;
        tok[threadIdx.x] = instr[b*TSEQ + tsel];
    }
    __syncthreads();
    for (int idx = threadIdx.x; idx < 16*EMBD; idx += 256) {
        int k = idx >> 4, r = idx & 15;
        rows_t[k][r] = etab[(size_t)tok[r]*EMBD + k];
    }
    __syncthreads();
    if (j >= GATE4) return;
    const float* Wx   = dir ? bWx : fWx;
    const float* bias = dir ? bb  : fb;
    float bv = bias[j];
    float acc[16];
    #pragma unroll
    for (int r = 0; r < 16; ++r) acc[r] = bv;
    for (int k = 0; k < EMBD; ++k) {
        float w = Wx[(size_t)k*GATE4 + j];
        float4 a0 = *reinterpret_cast<const float4*>(&rows_t[k][0]);
        float4 a1 = *reinterpret_cast<const float4*>(&rows_t[k][4]);
        float4 a2 = *reinterpret_cast<const float4*>(&rows_t[k][8]);
        float4 a3 = *reinterpret_cast<const float4*>(&rows_t[k][12]);
        acc[0]+=a0.x*w;  acc[1]+=a0.y*w;  acc[2]+=a0.z*w;  acc[3]+=a0.w*w;
        acc[4]+=a1.x*w;  acc[5]+=a1.y*w;  acc[6]+=a1.z*w;  acc[7]+=a1.w*w;
        acc[8]+=a2.x*w;  acc[9]+=a2.y*w;  acc[10]+=a2.z*w; acc[11]+=a2.w*w;
        acc[12]+=a3.x*w; acc[13]+=a3.y*w; acc[14]+=a3.z*w; acc[15]+=a3.w*w;
    }
    float* o = xg + ((size_t)(dir*BATCH + b)*TSEQ + t0)*GATE4 + j;
    #pragma unroll
    for (int r = 0; r < 16; ++r) o[(size_t)r*GATE4] = acc[r];
}

// ---- device-scope grid barrier (generation counter). Co-residency: 48KB LDS
// -> 3 blocks/CU -> 768 slots >= 300 blocks.
__device__ __forceinline__ void gridbar(int* bar, int nblk) {
    __threadfence();                 // release: drain stores, L2 writeback
    __syncthreads();
    if (threadIdx.x == 0) {
        int g = __hip_atomic_load(&bar[1], __ATOMIC_RELAXED, __HIP_MEMORY_SCOPE_AGENT);
        int v = __hip_atomic_fetch_add(&bar[0], 1, __ATOMIC_ACQ_REL, __HIP_MEMORY_SCOPE_AGENT);
        if (v == nblk - 1) {
            __hip_atomic_store(&bar[0], 0, __ATOMIC_RELAXED, __HIP_MEMORY_SCOPE_AGENT);
            __hip_atomic_fetch_add(&bar[1], 1, __ATOMIC_RELEASE, __HIP_MEMORY_SCOPE_AGENT);
        } else {
            while (__hip_atomic_load(&bar[1], __ATOMIC_ACQUIRE, __HIP_MEMORY_SCOPE_AGENT) == g)
                __builtin_amdgcn_s_sleep(8);
        }
        __threadfence();             // acquire: invalidate stale cache lines
    }
    __syncthreads();
}

// ---- persistent LSTM: all 128 steps, weights LDS-resident. grid 300, block 256 ----
__global__ __launch_bounds__(256)
void lstm_all(const float* __restrict__ xg, const float* __restrict__ whT,
              const int* __restrict__ lens,
              float* __restrict__ hbuf, float* __restrict__ tsum, int* bar)
{
    const int blk = blockIdx.x;
    const int dir = blk / 150;
    const int wid = threadIdx.x >> 6;
    const int u   = (blk % 150)*4 + wid;
    const int lane = threadIdx.x & 63;
    __shared__ float wlds[4][4][HIDD];   // 38.4 KB [wid][gate][k]
    __shared__ float hl[BATCH][HIDD];    // 9.6 KB
    const float* wr = whT + (size_t)dir*GATE4*HIDD;
    #pragma unroll
    for (int g = 0; g < 4; ++g)
        for (int k = lane; k < HIDD; k += 64)
            wlds[wid][g][k] = wr[(size_t)(g*HIDD + u)*HIDD + k];
    float creg = 0.f, tsreg = 0.f;
    int Lb = (lane < 4) ? lens[lane] : 0;
    __syncthreads();

    for (int t = 0; t < TSEQ; ++t) {
        float xv0=0.f, xv1=0.f, xv2=0.f, xv3=0.f;
        if (lane < 4) {
            const float* x = xg + ((size_t)(dir*BATCH + lane)*TSEQ + t)*GATE4;
            xv0 = x[u]; xv1 = x[HIDD+u]; xv2 = x[2*HIDD+u]; xv3 = x[3*HIDD+u];
        }
        const float* hprev = hbuf + (((size_t)(t&1)*2 + dir)*BATCH)*HIDD;
        for (int i = threadIdx.x; i < BATCH*HIDD; i += 256)
            hl[i/HIDD][i % HIDD] = hprev[i];
        __syncthreads();
        float acc[4][4] = {};
        #pragma unroll
        for (int i = 0; i < 10; ++i) {
            int k = i*64 + lane;
            if (k < HIDD) {
                float h0 = hl[0][k], h1 = hl[1][k], h2 = hl[2][k], h3 = hl[3][k];
                #pragma unroll
                for (int g = 0; g < 4; ++g) {
                    float w = wlds[wid][g][k];
                    acc[g][0] += w*h0; acc[g][1] += w*h1;
                    acc[g][2] += w*h2; acc[g][3] += w*h3;
                }
            }
        }
        #pragma unroll
        for (int off = 32; off; off >>= 1) {
            #pragma unroll
            for (int g = 0; g < 4; ++g) {
                acc[g][0] += __shfl_xor(acc[g][0], off, 64);
                acc[g][1] += __shfl_xor(acc[g][1], off, 64);
                acc[g][2] += __shfl_xor(acc[g][2], off, 64);
                acc[g][3] += __shfl_xor(acc[g][3], off, 64);
            }
        }
        if (lane < 4) {
            float g0 = lane==0?acc[0][0]:lane==1?acc[0][1]:lane==2?acc[0][2]:acc[0][3];
            float g1 = lane==0?acc[1][0]:lane==1?acc[1][1]:lane==2?acc[1][2]:acc[1][3];
            float g2 = lane==0?acc[2][0]:lane==1?acc[2][1]:lane==2?acc[2][2]:acc[2][3];
            float g3 = lane==0?acc[3][0]:lane==1?acc[3][1]:lane==2?acc[3][2]:acc[3][3];
            float ai = xv0 + g0, af = xv1 + g1, ac = xv2 + g2, ao = xv3 + g3;
            float si = 1.f/(1.f + expf(-ai));
            float sf = 1.f/(1.f + expf(-af));
            float so = 1.f/(1.f + expf(-ao));
            float cnew = sf*creg + si*tanhf(ac);
            float hnew = so*tanhf(cnew);
            creg = cnew;
            hbuf[(((size_t)((t+1)&1)*2 + dir)*BATCH + lane)*HIDD + u] = hnew;
            if (t < Lb) tsreg += hnew;
        }
        gridbar(bar, 300);
    }
    if (lane < 4)
        tsum[((size_t)dir*BATCH + lane)*HIDD + u] = tsreg;
}

// kern[which][b] = (tsum[which][b]/128) @ kW + kb
__global__ void kern_gemm(const float* __restrict__ tsum,
                          const float* __restrict__ k1W, const float* __restrict__ k1b,
                          const float* __restrict__ k2W, const float* __restrict__ k2b,
                          float* __restrict__ kern)
{
    int which = blockIdx.y;
    int co = blockIdx.x*256 + threadIdx.x;
    __shared__ float te[BATCH][HIDD];
    for (int i = threadIdx.x; i < BATCH*HIDD; i += 256) {
        int b = i / HIDD, k = i % HIDD;
        te[b][k] = tsum[((size_t)which*BATCH + b)*HIDD + k]*(1.f/128.f);
    }
    __syncthreads();
    const float* W    = which ? k2W : k1W;
    const float* bias = which ? k2b : k1b;
    float bv = bias[co];
    float a0=bv, a1=bv, a2=bv, a3=bv;
    for (int k = 0; k < HIDD; ++k) {
        float w = W[(size_t)k*16384 + co];
        a0 += te[0][k]*w; a1 += te[1][k]*w; a2 += te[2][k]*w; a3 += te[3][k]*w;
    }
    kern[((size_t)which*BATCH+0)*16384+co] = a0;
    kern[((size_t)which*BATCH+1)*16384+co] = a1;
    kern[((size_t)which*BATCH+2)*16384+co] = a2;
    kern[((size_t)which*BATCH+3)*16384+co] = a3;
}

// ---- MFMA 5x5 SAME conv, f16 hi/lo 3-term ----
template<int MODE>
__global__ __launch_bounds__(256)
void conv5m(const float* __restrict__ src, const _Float16* __restrict__ whi,
            const _Float16* __restrict__ wlo, const float* __restrict__ bias,
            float* __restrict__ dst)
{
    __shared__ _Float16 lds[2*20480];
    const int tid = threadIdx.x;
    const int b  = blockIdx.z;
    const int r0 = blockIdx.y*4, p0 = blockIdx.x*16;
    const size_t rowS = (size_t)WW*CC, imgS = (size_t)HH*rowS;
    const float* sb = src + (size_t)b*imgS;

    for (int it = 0; it < 20; ++it) {
        int idx = it*256 + tid;
        int c4  = idx & 31;
        int px  = (idx >> 5) % 20;
        int row = idx / 640;
        int gr = r0 + row - 2, gp = p0 + px - 2;
        float4 v = make_float4(0.f,0.f,0.f,0.f);
        if ((unsigned)gr < HH && (unsigned)gp < WW)
            v = *reinterpret_cast<const float4*>(sb + (size_t)gr*rowS + (size_t)gp*CC + c4*4);
        int pix = row*20 + px;
        int ph  = (pix*128 + c4*4) ^ ((pix & 7) << 3);
        _Float16 h0=(_Float16)v.x, h1=(_Float16)v.y, h2=(_Float16)v.z, h3=(_Float16)v.w;
        f16x4 hv = {h0, h1, h2, h3};
        f16x4 lv = {(_Float16)(v.x-(float)h0), (_Float16)(v.y-(float)h1),
                    (_Float16)(v.z-(float)h2), (_Float16)(v.w-(float)h3)};
        *reinterpret_cast<f16x4*>(&lds[ph]) = hv;
        *reinterpret_cast<f16x4*>(&lds[20480 + ph]) = lv;
    }
    __syncthreads();

    const int lane = tid & 63, w = tid >> 6;
    const int wm = w & 1, wn = w >> 1;
    const int l15 = lane & 15, kg = lane >> 4;

    f32x4 acc[2][4];
    #pragma unroll
    for (int mi = 0; mi < 2; ++mi)
        #pragma unroll
        for (int ni = 0; ni < 4; ++ni)
            acc[mi][ni] = (f32x4){0.f,0.f,0.f,0.f};

    for (int dy = 0; dy < 5; ++dy) {
        for (int dx = 0; dx < 5; ++dx) {
            const int tap = dy*5 + dx;
            const _Float16* wth = whi + ((size_t)tap << 14) + wn*8192 + lane*8;
            const _Float16* wtl = wlo + ((size_t)tap << 14) + wn*8192 + lane*8;
            int pix0 = (wm*2 + dy)*20 + l15 + dx;
            int a0 = pix0*128 + kg*8;       int sw0 = (pix0 & 7) << 3;
            int pix1 = pix0 + 20;
            int a1 = pix1*128 + kg*8;       int sw1 = (pix1 & 7) << 3;
            for (int kt = 0; kt < 4; ++kt) {
                const _Float16* ph = wth + kt*2048;
                const _Float16* pl = wtl + kt*2048;
                f16x8 bh0 = *(const f16x8*)(ph);
                f16x8 bh1 = *(const f16x8*)(ph + 512);
                f16x8 bh2 = *(const f16x8*)(ph + 1024);
                f16x8 bh3 = *(const f16x8*)(ph + 1536);
                f16x8 bl0 = *(const f16x8*)(pl);
                f16x8 bl1 = *(const f16x8*)(pl + 512);
                f16x8 bl2 = *(const f16x8*)(pl + 1024);
                f16x8 bl3 = *(const f16x8*)(pl + 1536);
                f16x8 ah0 = *(const f16x8*)&lds[(a0 + kt*32) ^ sw0];
                f16x8 al0 = *(const f16x8*)&lds[20480 + ((a0 + kt*32) ^ sw0)];
                f16x8 ah1 = *(const f16x8*)&lds[(a1 + kt*32) ^ sw1];
                f16x8 al1 = *(const f16x8*)&lds[20480 + ((a1 + kt*32) ^ sw1)];
#define SPLIT_MFMA(mi, ni, AH, AL, BH, BL)                                          \
    acc[mi][ni] = __builtin_amdgcn_mfma_f32_16x16x32_f16(AH, BH, acc[mi][ni],0,0,0);\
    acc[mi][ni] = __builtin_amdgcn_mfma_f32_16x16x32_f16(AH, BL, acc[mi][ni],0,0,0);\
    acc[mi][ni] = __builtin_amdgcn_mfma_f32_16x16x32_f16(AL, BH, acc[mi][ni],0,0,0);
                SPLIT_MFMA(0,0, ah0, al0, bh0, bl0)
                SPLIT_MFMA(0,1, ah0, al0, bh1, bl1)
                SPLIT_MFMA(0,2, ah0, al0, bh2, bl2)
                SPLIT_MFMA(0,3, ah0, al0, bh3, bl3)
                SPLIT_MFMA(1,0, ah1, al1, bh0, bl0)
                SPLIT_MFMA(1,1, ah1, al1, bh1, bl1)
                SPLIT_MFMA(1,2, ah1, al1, bh2, bl2)
                SPLIT_MFMA(1,3, ah1, al1, bh3, bl3)
#undef SPLIT_MFMA
            }
        }
    }

    #pragma unroll
    for (int ni = 0; ni < 4; ++ni) {
        int oc = wn*64 + ni*16 + l15;
        float bv = (MODE != 0) ? bias[oc] : 0.f;
        #pragma unroll
        for (int mi = 0; mi < 2; ++mi) {
            float* op = dst + (size_t)b*imgS + (size_t)(r0 + wm*2 + mi)*rowS
                            + (size_t)(p0 + kg*4)*CC + oc;
            f32x4 a = acc[mi][ni];
            #pragma unroll
            for (int q = 0; q < 4; ++q) {
                float v = a[q];
                float* ap = op + (size_t)q*CC;
                if (MODE == 0)      *ap = v;
                else if (MODE == 1) *ap = fmaxf(v + bv, 0.f);
                else                *ap = fmaxf(v + *ap + bv, 0.f);
            }
        }
    }
}

// ---- MFMA chanmul: 128 px/block, no LDS, raw store ----
__global__ __launch_bounds__(256)
void chanmul_mfma(const float* __restrict__ src, const _Float16* __restrict__ kf,
                  float* __restrict__ dst)
{
    const int tid = threadIdx.x;
    const int lane = tid & 63, w = tid >> 6;
    const int l15 = lane & 15, kg = lane >> 4;
    const int b = blockIdx.y;
    const size_t pxbase = (size_t)blockIdx.x*128 + w*32;
    if (pxbase >= NPIX) return;
    const float* X = src + (size_t)b*NPIX*CC;
    const _Float16* wb = kf + (size_t)b*32768;

    f32x4 acc[2][8];
    #pragma unroll
    for (int ni = 0; ni < 8; ++ni) {
        acc[0][ni] = (f32x4){0.f,0.f,0.f,0.f};
        acc[1][ni] = (f32x4){0.f,0.f,0.f,0.f};
    }
    #pragma unroll
    for (int kt = 0; kt < 4; ++kt) {
        f16x8 ah0, al0, ah1, al1;
        {
            const float* xp = X + (pxbase + l15)*CC + kt*32 + kg*8;
            cvt8(*(const float4*)xp, *(const float4*)(xp+4), ah0, al0);
            const float* xq = xp + 16*CC;
            cvt8(*(const float4*)xq, *(const float4*)(xq+4), ah1, al1);
        }
        #pragma unroll
        for (int ni = 0; ni < 8; ++ni) {
            const _Float16* bp = wb + (((size_t)kt*8 + ni)*64 + lane)*8;
            f16x8 bh = *(const f16x8*)bp;
            f16x8 bl = *(const f16x8*)(bp + 16384);
            acc[0][ni] = __builtin_amdgcn_mfma_f32_16x16x32_f16(ah0, bh, acc[0][ni],0,0,0);
            acc[0][ni] = __builtin_amdgcn_mfma_f32_16x16x32_f16(ah0, bl, acc[0][ni],0,0,0);
            acc[0][ni] = __builtin_amdgcn_mfma_f32_16x16x32_f16(al0, bh, acc[0][ni],0,0,0);
            acc[1][ni] = __builtin_amdgcn_mfma_f32_16x16x32_f16(ah1, bh, acc[1][ni],0,0,0);
            acc[1][ni] = __builtin_amdgcn_mfma_f32_16x16x32_f16(ah1, bl, acc[1][ni],0,0,0);
            acc[1][ni] = __builtin_amdgcn_mfma_f32_16x16x32_f16(al1, bh, acc[1][ni],0,0,0);
        }
    }
    #pragma unroll
    for (int mi = 0; mi < 2; ++mi)
        #pragma unroll
        for (int ni = 0; ni < 8; ++ni) {
            f32x4 a = acc[mi][ni];
            #pragma unroll
            for (int q = 0; q < 4; ++q) {
                size_t px = pxbase + mi*16 + kg*4 + q;
                dst[((size_t)b*NPIX + px)*CC + ni*16 + l15] = a[q];
            }
        }
}

// ---- MFMA head (validated round 6) ----
__global__ __launch_bounds__(256)
void head_mfma(const float* __restrict__ X, const _Float16* __restrict__ whd,
               const float* __restrict__ d1b, const float* __restrict__ d2b,
               const float* __restrict__ oW, float* __restrict__ out)
{
    __shared__ float o1s[4][4096];
    const int tid = threadIdx.x;
    const int lane = tid & 63, w = tid >> 6;
    const int l15 = lane & 15, kg = lane >> 4;
    const size_t pxbase = (size_t)blockIdx.x*128 + w*32;
    float* o1w = o1s[w];

    const _Float16* w1 = whd;
    const _Float16* w2 = whd + 32768;

    f32x4 acc[2][8];
    #pragma unroll
    for (int ni = 0; ni < 8; ++ni) {
        float bv = d1b[ni*16 + l15];
        acc[0][ni] = (f32x4){bv,bv,bv,bv};
        acc[1][ni] = (f32x4){bv,bv,bv,bv};
    }
    #pragma unroll
    for (int kt = 0; kt < 4; ++kt) {
        f16x8 ah0, al0, ah1, al1;
        {
            const float* xp = X + (pxbase + l15)*CC + kt*32 + kg*8;
            cvt8(*(const float4*)xp, *(const float4*)(xp+4), ah0, al0);
            const float* xq = xp + 16*CC;
            cvt8(*(const float4*)xq, *(const float4*)(xq+4), ah1, al1);
        }
        #pragma unroll
        for (int ni = 0; ni < 8; ++ni) {
            const _Float16* bp = w1 + (((size_t)kt*8 + ni)*64 + lane)*8;
            f16x8 bh = *(const f16x8*)bp;
            f16x8 bl = *(const f16x8*)(bp + 16384);
            acc[0][ni] = __builtin_amdgcn_mfma_f32_16x16x32_f16(ah0, bh, acc[0][ni],0,0,0);
            acc[0][ni] = __builtin_amdgcn_mfma_f32_16x16x32_f16(ah0, bl, acc[0][ni],0,0,0);
            acc[0][ni] = __builtin_amdgcn_mfma_f32_16x16x32_f16(al0, bh, acc[0][ni],0,0,0);
            acc[1][ni] = __builtin_amdgcn_mfma_f32_16x16x32_f16(ah1, bh, acc[1][ni],0,0,0);
            acc[1][ni] = __builtin_amdgcn_mfma_f32_16x16x32_f16(ah1, bl, acc[1][ni],0,0,0);
            acc[1][ni] = __builtin_amdgcn_mfma_f32_16x16x32_f16(al1, bh, acc[1][ni],0,0,0);
        }
    }
    #pragma unroll
    for (int mi = 0; mi < 2; ++mi)
        #pragma unroll
        for (int ni = 0; ni < 8; ++ni) {
            f32x4 a = acc[mi][ni];
            #pragma unroll
            for (int q = 0; q < 4; ++q) {
                int px = mi*16 + kg*4 + q;
                int oc = ni*16 + l15;
                o1w[(px*128 + oc) ^ ((px & 7) << 3)] = fmaxf(a[q], 0.f);
            }
        }

    f32x4 acc2[2][8];
    #pragma unroll
    for (int ni = 0; ni < 8; ++ni) {
        float bv = d2b[ni*16 + l15];
        acc2[0][ni] = (f32x4){bv,bv,bv,bv};
        acc2[1][ni] = (f32x4){bv,bv,bv,bv};
    }
    #pragma unroll
    for (int kt = 0; kt < 4; ++kt) {
        f16x8 ah0, al0, ah1, al1;
        {
            int px0 = l15;
            int i0 = (px0*128 + kt*32 + kg*8) ^ ((px0 & 7) << 3);
            cvt8(*(const float4*)&o1w[i0], *(const float4*)&o1w[i0+4], ah0, al0);
            int px1 = 16 + l15;
            int i1 = (px1*128 + kt*32 + kg*8) ^ ((px1 & 7) << 3);
            cvt8(*(const float4*)&o1w[i1], *(const float4*)&o1w[i1+4], ah1, al1);
        }
        #pragma unroll
        for (int ni = 0; ni < 8; ++ni) {
            const _Float16* bp = w2 + (((size_t)kt*8 + ni)*64 + lane)*8;
            f16x8 bh = *(const f16x8*)bp;
            f16x8 bl = *(const f16x8*)(bp + 16384);
            acc2[0][ni] = __builtin_amdgcn_mfma_f32_16x16x32_f16(ah0, bh, acc2[0][ni],0,0,0);
            acc2[0][ni] = __builtin_amdgcn_mfma_f32_16x16x32_f16(ah0, bl, acc2[0][ni],0,0,0);
            acc2[0][ni] = __builtin_amdgcn_mfma_f32_16x16x32_f16(al0, bh, acc2[0][ni],0,0,0);
            acc2[1][ni] = __builtin_amdgcn_mfma_f32_16x16x32_f16(ah1, bh, acc2[1][ni],0,0,0);
            acc2[1][ni] = __builtin_amdgcn_mfma_f32_16x16x32_f16(ah1, bl, acc2[1][ni],0,0,0);
            acc2[1][ni] = __builtin_amdgcn_mfma_f32_16x16x32_f16(al1, bh, acc2[1][ni],0,0,0);
        }
    }

    #pragma unroll
    for (int mi = 0; mi < 2; ++mi) {
        float p0 = 0.f, p1 = 0.f, p2 = 0.f, p3 = 0.f;
        #pragma unroll
        for (int ni = 0; ni < 8; ++ni) {
            float ow = oW[ni*16 + l15];
            f32x4 a = acc2[mi][ni];
            p0 += fmaxf(a[0], 0.f)*ow;
            p1 += fmaxf(a[1], 0.f)*ow;
            p2 += fmaxf(a[2], 0.f)*ow;
            p3 += fmaxf(a[3], 0.f)*ow;
        }
        #pragma unroll
        for (int off = 1; off < 16; off <<= 1) {
            p0 += __shfl_xor(p0, off, 64);
            p1 += __shfl_xor(p1, off, 64);
            p2 += __shfl_xor(p2, off, 64);
            p3 += __shfl_xor(p3, off, 64);
        }
        if (l15 == 0) {
            float* op = out + pxbase + mi*16 + kg*4;
            op[0] = p0; op[1] = p1; op[2] = p2; op[3] = p3;
        }
    }
}

// in-place softmax over rows of 46400
__global__ void softmax_rows(float* __restrict__ out)
{
    int b = blockIdx.x;
    float* row = out + (size_t)b*NPIX;
    __shared__ float red[16];
    float m = -3.4e38f;
    for (int i = threadIdx.x; i < NPIX; i += 1024) m = fmaxf(m, row[i]);
    for (int o = 32; o; o >>= 1) m = fmaxf(m, __shfl_down(m, o, 64));
    if ((threadIdx.x & 63) == 0) red[threadIdx.x >> 6] = m;
    __syncthreads();
    if (threadIdx.x == 0) {
        float mm = red[0];
        for (int i = 1; i < 16; ++i) mm = fmaxf(mm, red[i]);
        red[0] = mm;
    }
    __syncthreads();
    m = red[0];
    __syncthreads();
    float s = 0.f;
    for (int i = threadIdx.x; i < NPIX; i += 1024) s += expf(row[i] - m);
    for (int o = 32; o; o >>= 1) s += __shfl_down(s, o, 64);
    if ((threadIdx.x & 63) == 0) red[threadIdx.x >> 6] = s;
    __syncthreads();
    if (threadIdx.x == 0) {
        float ss = 0.f;
        for (int i = 0; i < 16; ++i) ss += red[i];
        red[0] = ss;
    }
    __syncthreads();
    float inv = 1.f/red[0];
    for (int i = threadIdx.x; i < NPIX; i += 1024) row[i] = expf(row[i] - m)*inv;
}

extern "C" void kernel_launch(void* const* d_in, const int* in_sizes, int n_in,
                              void* d_out, int out_size, void* d_ws, size_t ws_size,
                              hipStream_t stream) {
    (void)in_sizes; (void)n_in; (void)out_size; (void)ws_size;
    const float* img  = (const float*)d_in[0];
    const int* instr  = (const int*)d_in[1];
    const int* lens   = (const int*)d_in[2];
    const float* etab = (const float*)d_in[3];
    const float* fWx  = (const float*)d_in[4];
    const float* fWh  = (const float*)d_in[5];
    const float* fb   = (const float*)d_in[6];
    const float* bWx  = (const float*)d_in[7];
    const float* bWh  = (const float*)d_in[8];
    const float* bb   = (const float*)d_in[9];
    const float* k1W  = (const float*)d_in[10];
    const float* k1b  = (const float*)d_in[11];
    const float* k2W  = (const float*)d_in[12];
    const float* k2b  = (const float*)d_in[13];
    const float* c1w  = (const float*)d_in[14];
    const float* c1b  = (const float*)d_in[15];
    const float* c2w  = (const float*)d_in[16];
    const float* c2b  = (const float*)d_in[17];
    const float* dc1w = (const float*)d_in[18];
    const float* dc1b = (const float*)d_in[19];
    const float* dc2w = (const float*)d_in[20];
    const float* dc2b = (const float*)d_in[21];
    const float* d1W  = (const float*)d_in[22];
    const float* d1b  = (const float*)d_in[23];
    const float* d2W  = (const float*)d_in[24];
    const float* d2b  = (const float*)d_in[25];
    const float* oW   = (const float*)d_in[26];
    float* out = (float*)d_out;
    float* ws  = (float*)d_ws;

    float* A  = ws + OFF_A;
    float* Bb = ws + OFF_B;
    float* Cb = ws + OFF_C;
    float* xg = ws + OFF_XG;
    float* hb = ws + OFF_H;
    int*   bar = (int*)(ws + OFF_CS);
    float* ts = ws + OFF_TS;
    float* kn = ws + OFF_K;
    _Float16* whi = (_Float16*)(ws + OFF_W);
    _Float16* wlo = whi + WELEMS;
    _Float16* whd = (_Float16*)(ws + OFF_WH);
    _Float16* kf  = (_Float16*)(ws + OFF_KF);
    float* whT = Cb;   // overlay: dead until chanmul writes g1

    wcvt<<<WELEMS/256, 256, 0, stream>>>(c1w, c2w, dc2w, dc1w, whi, wlo);
    wcvt_head<<<128, 256, 0, stream>>>(d1W, d2W, whd);
    wh_t<<<dim3(10, 2), 256, 0, stream>>>(fWh, bWh, whT);
    zero_f<<<dim3((int)((SZ_H + 8 + 255)/256)), 256, 0, stream>>>(hb, (int)(SZ_H + 8));
    embed_xg<<<dim3(10, 64), 256, 0, stream>>>(instr, lens, etab, fWx, fb, bWx, bb, xg);
    // full recurrence in ONE persistent kernel (Wh LDS-resident, grid barrier)
    lstm_all<<<300, 256, 0, stream>>>(xg, whT, lens, hb, ts, bar);
    kern_gemm<<<dim3(64, 2), 256, 0, stream>>>(ts, k1W, k1b, k2W, k2b, kn);
    kcvt<<<512, 256, 0, stream>>>(kn, kf);
    dim3 cgrid(WW/16, HH/4, BATCH);   // (29, 25, 4)
    conv5m<1><<<cgrid, 256, 0, stream>>>(img, whi + 0*WSLOT, wlo + 0*WSLOT, c1b, A);    // f1 -> A
    conv5m<1><<<cgrid, 256, 0, stream>>>(A,   whi + 1*WSLOT, wlo + 1*WSLOT, c2b, Bb);   // f2 -> B
    chanmul_mfma<<<dim3(363, BATCH), 256, 0, stream>>>(A,  kf,           Cb);  // g1 -> C (kills WhT)
    chanmul_mfma<<<dim3(363, BATCH), 256, 0, stream>>>(Bb, kf + 4*32768, A);   // g2 -> A
    conv5m<1><<<cgrid, 256, 0, stream>>>(A,  whi + 2*WSLOT, wlo + 2*WSLOT, dc2b, Bb);   // h2 -> B
    conv5m<0><<<cgrid, 256, 0, stream>>>(Bb, whi + 3*WSLOT, wlo + 3*WSLOT, dc1b, A);    // h1 partial
    conv5m<2><<<cgrid, 256, 0, stream>>>(Cb, whi + 4*WSLOT, wlo + 4*WSLOT, dc1b, A);    // h1 += g1, bias+relu
    head_mfma<<<1450, 256, 0, stream>>>(A, whd, d1b, d2b, oW, out);
    softmax_rows<<<dim3(BATCH), 1024, 0, stream>>>(out);
}